// Round 1
// baseline (2078.039 us; speedup 1.0000x reference)
//
#include <hip/hip_runtime.h>
#include <cstdint>

#define HD 4096
#define FF 11008
#define BB 2
#define LL 2048
#define BL (BB*LL)

using bf16x8  = __attribute__((ext_vector_type(8))) __bf16;
using f32x4   = __attribute__((ext_vector_type(4))) float;
using ushort8 = __attribute__((ext_vector_type(8))) unsigned short;

__device__ __forceinline__ int imin(int a, int b) { return a < b ? a : b; }

__device__ __forceinline__ unsigned short f2bf(float f) {
  union { float f; unsigned u; } v; v.f = f;
  unsigned r = v.u + 0x7fffu + ((v.u >> 16) & 1u);
  return (unsigned short)(r >> 16);
}

__device__ __forceinline__ void gld_lds16(const void* g, void* l) {
  __builtin_amdgcn_global_load_lds(
      (__attribute__((address_space(1))) void*)g,
      (__attribute__((address_space(3))) void*)l, 16, 0, 0);
}

// ---- detect int32 vs int64 storage of token_type_ids ----
__global__ void detect_mode(const int* __restrict__ w, int* __restrict__ flag) {
  int acc = 0;
  for (int i = 1 + 2 * (int)threadIdx.x; i < BL; i += 512) acc |= w[i];
  if (acc != 0) atomicOr(flag, 1);
}

// ---- vision mask + index compaction ----
__global__ void mask_compact(const int* __restrict__ w, const int* __restrict__ flag,
                             int* __restrict__ cnts, int* __restrict__ idxL,
                             int* __restrict__ idxV) {
  int i = blockIdx.x * 256 + threadIdx.x;
  if (i >= BL) return;
  int p = i & (LL - 1);
  bool i32 = (*flag != 0);
  int ti = i32 ? w[i] : w[2 * i];
  bool vis = false;
  if (p < LL - 1) {
    int tn = i32 ? w[i + 1] : w[2 * (i + 1)];
    vis = (ti == 1) && (tn == 1);
  }
  if (vis) idxV[atomicAdd(&cnts[1], 1)] = i;
  else     idxL[atomicAdd(&cnts[0], 1)] = i;
}

// ---- hidden_states fp32 -> bf16 ----
__global__ void convx(const float* __restrict__ x, unsigned short* __restrict__ xb) {
  size_t i = ((size_t)blockIdx.x * 256 + threadIdx.x) * 8;
  float4 a = *(const float4*)(x + i);
  float4 b = *(const float4*)(x + i + 4);
  ushort8 o;
  o[0] = f2bf(a.x); o[1] = f2bf(a.y); o[2] = f2bf(a.z); o[3] = f2bf(a.w);
  o[4] = f2bf(b.x); o[5] = f2bf(b.y); o[6] = f2bf(b.z); o[7] = f2bf(b.w);
  *(ushort8*)(xb + i) = o;
}

// ---- weight transpose + convert: in [K][N] fp32 -> out [N][K] bf16 ----
__global__ void convT(const float* __restrict__ in, unsigned short* __restrict__ out,
                      int K, int N) {
  __shared__ unsigned short T[64][65];
  int n0 = blockIdx.x * 64, k0 = blockIdx.y * 64;
  int t = threadIdx.x;
  int cg = (t & 15) * 4;
  int r0 = t >> 4;
#pragma unroll
  for (int it = 0; it < 4; ++it) {
    int r = r0 + it * 16;
    float4 v = *(const float4*)(in + (size_t)(k0 + r) * N + n0 + cg);
    T[cg + 0][r] = f2bf(v.x); T[cg + 1][r] = f2bf(v.y);
    T[cg + 2][r] = f2bf(v.z); T[cg + 3][r] = f2bf(v.w);
  }
  __syncthreads();
  int nl = t >> 3, kg = t & 7;
#pragma unroll
  for (int it = 0; it < 2; ++it) {
    int n = nl + it * 32;
    ushort8 o;
#pragma unroll
    for (int j = 0; j < 8; ++j) o[j] = T[n][kg * 8 + j];
    *(ushort8*)(out + (size_t)(n0 + n) * K + k0 + kg * 8) = o;
  }
}

// ---- GEMM1: h = silu(x@Wg) * (x@Wu), gathered rows, 128x64 tile, BK=64 ----
__global__ __launch_bounds__(256) void gemm1(
    const unsigned short* __restrict__ Xb, const unsigned short* __restrict__ Wg,
    const unsigned short* __restrict__ Wu, const int* __restrict__ idx,
    const int* __restrict__ cntp, unsigned short* __restrict__ H) {
  const int cnt = *cntp;
  const int m0 = blockIdx.y * 128;
  if (m0 >= cnt) return;
  const int n0 = blockIdx.x * 64;

  __shared__ __align__(16) unsigned short sA[128 * 64];
  __shared__ __align__(16) unsigned short sBg[64 * 64];
  __shared__ __align__(16) unsigned short sBu[64 * 64];

  const int t = threadIdx.x, l = t & 63, w = t >> 6;
  const int wr = w >> 1, wc = w & 1;
  const int c = l & 7, lr = l >> 3;
  const int choff = ((c ^ lr) << 3);   // pre-swizzled source chunk (m173 pattern)

  int tokA[4];
#pragma unroll
  for (int i = 0; i < 4; ++i)
    tokA[i] = idx[imin(m0 + (w * 4 + i) * 8 + lr, cnt - 1)];
  int rowB[2];
#pragma unroll
  for (int i = 0; i < 2; ++i) rowB[i] = (w * 2 + i) * 8 + lr;

  int offA[2][4], offB[2][2];
#pragma unroll
  for (int kk = 0; kk < 2; ++kk) {
#pragma unroll
    for (int mi = 0; mi < 4; ++mi) {
      int m = wr * 64 + mi * 16 + (l & 15);
      offA[kk][mi] = m * 64 + ((((kk << 2) + (l >> 4)) ^ (m & 7)) << 3);
    }
#pragma unroll
    for (int ni = 0; ni < 2; ++ni) {
      int n = wc * 32 + ni * 16 + (l & 15);
      offB[kk][ni] = n * 64 + ((((kk << 2) + (l >> 4)) ^ (n & 7)) << 3);
    }
  }

  f32x4 accg[4][2] = {};
  f32x4 accu[4][2] = {};

  for (int k0 = 0; k0 < HD; k0 += 64) {
#pragma unroll
    for (int i = 0; i < 4; ++i)
      gld_lds16(Xb + (size_t)tokA[i] * HD + k0 + choff, &sA[(w * 4 + i) * 512]);
#pragma unroll
    for (int i = 0; i < 2; ++i) {
      gld_lds16(Wg + (size_t)(n0 + rowB[i]) * HD + k0 + choff, &sBg[(w * 2 + i) * 512]);
      gld_lds16(Wu + (size_t)(n0 + rowB[i]) * HD + k0 + choff, &sBu[(w * 2 + i) * 512]);
    }
    __syncthreads();
#pragma unroll
    for (int kk = 0; kk < 2; ++kk) {
      bf16x8 a[4], bg[2], bu[2];
#pragma unroll
      for (int mi = 0; mi < 4; ++mi) a[mi] = *(const bf16x8*)&sA[offA[kk][mi]];
#pragma unroll
      for (int ni = 0; ni < 2; ++ni) {
        bg[ni] = *(const bf16x8*)&sBg[offB[kk][ni]];
        bu[ni] = *(const bf16x8*)&sBu[offB[kk][ni]];
      }
#pragma unroll
      for (int mi = 0; mi < 4; ++mi)
#pragma unroll
        for (int ni = 0; ni < 2; ++ni) {
          accg[mi][ni] = __builtin_amdgcn_mfma_f32_16x16x32_bf16(a[mi], bg[ni], accg[mi][ni], 0, 0, 0);
          accu[mi][ni] = __builtin_amdgcn_mfma_f32_16x16x32_bf16(a[mi], bu[ni], accu[mi][ni], 0, 0, 0);
        }
    }
    __syncthreads();
  }

#pragma unroll
  for (int mi = 0; mi < 4; ++mi)
#pragma unroll
    for (int j = 0; j < 4; ++j) {
      int grow = m0 + wr * 64 + mi * 16 + ((l >> 4) << 2) + j;
      if (grow < cnt) {
        int token = idx[grow];
        size_t base = (size_t)token * FF + n0 + wc * 32 + (l & 15);
#pragma unroll
        for (int ni = 0; ni < 2; ++ni) {
          float g = accg[mi][ni][j];
          float u = accu[mi][ni][j];
          float h = (g / (1.f + __expf(-g))) * u;
          H[base + ni * 16] = f2bf(h);
        }
      }
    }
}

// ---- GEMM2: out = h @ Wd, gathered rows, 128x128 tile, BK=64 ----
__global__ __launch_bounds__(256) void gemm2(
    const unsigned short* __restrict__ Hh, const unsigned short* __restrict__ Wd,
    const int* __restrict__ idx, const int* __restrict__ cntp,
    float* __restrict__ Out) {
  const int cnt = *cntp;
  const int m0 = blockIdx.y * 128;
  if (m0 >= cnt) return;
  const int n0 = blockIdx.x * 128;

  __shared__ __align__(16) unsigned short sA[128 * 64];
  __shared__ __align__(16) unsigned short sB[128 * 64];

  const int t = threadIdx.x, l = t & 63, w = t >> 6;
  const int wr = w >> 1, wc = w & 1;
  const int c = l & 7, lr = l >> 3;
  const int choff = ((c ^ lr) << 3);

  int tokA[4];
#pragma unroll
  for (int i = 0; i < 4; ++i)
    tokA[i] = idx[imin(m0 + (w * 4 + i) * 8 + lr, cnt - 1)];

  int offA[2][4], offB[2][4];
#pragma unroll
  for (int kk = 0; kk < 2; ++kk) {
#pragma unroll
    for (int mi = 0; mi < 4; ++mi) {
      int m = wr * 64 + mi * 16 + (l & 15);
      offA[kk][mi] = m * 64 + ((((kk << 2) + (l >> 4)) ^ (m & 7)) << 3);
    }
#pragma unroll
    for (int ni = 0; ni < 4; ++ni) {
      int n = wc * 64 + ni * 16 + (l & 15);
      offB[kk][ni] = n * 64 + ((((kk << 2) + (l >> 4)) ^ (n & 7)) << 3);
    }
  }

  f32x4 acc[4][4] = {};

  for (int k0 = 0; k0 < FF; k0 += 64) {
#pragma unroll
    for (int i = 0; i < 4; ++i)
      gld_lds16(Hh + (size_t)tokA[i] * FF + k0 + choff, &sA[(w * 4 + i) * 512]);
#pragma unroll
    for (int i = 0; i < 4; ++i) {
      int n = (w * 4 + i) * 8 + lr;
      gld_lds16(Wd + (size_t)(n0 + n) * FF + k0 + choff, &sB[(w * 4 + i) * 512]);
    }
    __syncthreads();
#pragma unroll
    for (int kk = 0; kk < 2; ++kk) {
      bf16x8 a[4], b[4];
#pragma unroll
      for (int mi = 0; mi < 4; ++mi) a[mi] = *(const bf16x8*)&sA[offA[kk][mi]];
#pragma unroll
      for (int ni = 0; ni < 4; ++ni) b[ni] = *(const bf16x8*)&sB[offB[kk][ni]];
#pragma unroll
      for (int mi = 0; mi < 4; ++mi)
#pragma unroll
        for (int ni = 0; ni < 4; ++ni)
          acc[mi][ni] = __builtin_amdgcn_mfma_f32_16x16x32_bf16(a[mi], b[ni], acc[mi][ni], 0, 0, 0);
    }
    __syncthreads();
  }

#pragma unroll
  for (int mi = 0; mi < 4; ++mi)
#pragma unroll
    for (int j = 0; j < 4; ++j) {
      int grow = m0 + wr * 64 + mi * 16 + ((l >> 4) << 2) + j;
      if (grow < cnt) {
        int token = idx[grow];
        size_t base = (size_t)token * HD + n0 + wc * 64 + (l & 15);
#pragma unroll
        for (int ni = 0; ni < 4; ++ni)
          Out[base + ni * 16] = acc[mi][ni][j];
      }
    }
}

extern "C" void kernel_launch(void* const* d_in, const int* in_sizes, int n_in,
                              void* d_out, int out_size, void* d_ws, size_t ws_size,
                              hipStream_t stream) {
  const float* hs = (const float*)d_in[0];
  const int*   tt = (const int*)d_in[1];
  const float* lg = (const float*)d_in[2];
  const float* lu = (const float*)d_in[3];
  const float* ld = (const float*)d_in[4];
  const float* vg = (const float*)d_in[5];
  const float* vu = (const float*)d_in[6];
  const float* vd = (const float*)d_in[7];
  float* out = (float*)d_out;
  char* ws = (char*)d_ws;

  int* cnts = (int*)ws;            // [0]=lang count, [1]=vis count
  int* flag = (int*)(ws + 8);      // int32/int64 mode flag
  int* idxL = (int*)(ws + 1024);
  int* idxV = (int*)(ws + 1024 + BL * 4);
  unsigned short* Xb = (unsigned short*)(ws + 65536);
  unsigned short* Hb = Xb + (size_t)BL * HD;
  unsigned short* W0 = Hb + (size_t)BL * FF;
  unsigned short* W1 = W0 + (size_t)HD * FF;
  // total ws use: 65536 + 33.6MB + 90.2MB + 2*90.2MB ~= 304MB

  hipMemsetAsync(ws, 0, 64, stream);
  detect_mode<<<1, 256, 0, stream>>>(tt, flag);
  mask_compact<<<BL / 256, 256, 0, stream>>>(tt, flag, cnts, idxL, idxV);
  convx<<<(BL * HD / 8) / 256, 256, 0, stream>>>(hs, Xb);

  // lang expert: gate+up -> h
  convT<<<dim3(FF / 64, HD / 64), 256, 0, stream>>>(lg, W0, HD, FF);
  convT<<<dim3(FF / 64, HD / 64), 256, 0, stream>>>(lu, W1, HD, FF);
  gemm1<<<dim3(FF / 64, BL / 128), 256, 0, stream>>>(Xb, W0, W1, idxL, cnts + 0, Hb);
  // vis expert: gate+up -> h
  convT<<<dim3(FF / 64, HD / 64), 256, 0, stream>>>(vg, W0, HD, FF);
  convT<<<dim3(FF / 64, HD / 64), 256, 0, stream>>>(vu, W1, HD, FF);
  gemm1<<<dim3(FF / 64, BL / 128), 256, 0, stream>>>(Xb, W0, W1, idxV, cnts + 1, Hb);
  // down projections
  convT<<<dim3(HD / 64, FF / 64), 256, 0, stream>>>(ld, W0, FF, HD);
  gemm2<<<dim3(HD / 128, BL / 128), 256, 0, stream>>>(Hb, W0, idxL, cnts + 0, out);
  convT<<<dim3(HD / 64, FF / 64), 256, 0, stream>>>(vd, W0, FF, HD);
  gemm2<<<dim3(HD / 128, BL / 128), 256, 0, stream>>>(Hb, W0, idxV, cnts + 1, out);
}